// Round 1
// baseline (562.832 us; speedup 1.0000x reference)
//
#include <hip/hip_runtime.h>
#include <stdint.h>
#include <math.h>

typedef __attribute__((ext_vector_type(8))) short short8;
typedef __attribute__((ext_vector_type(4))) float f32x4;

#define DEV __device__ __forceinline__

DEV unsigned short f2bf(float f) {
  union { float f; unsigned int u; } v; v.f = f;
  return (unsigned short)((v.u + 0x7FFFu + ((v.u >> 16) & 1u)) >> 16);
}

DEV void gld16(const void* g, void* lds) {
  __builtin_amdgcn_global_load_lds(
      (const __attribute__((address_space(1))) unsigned int*)g,
      (__attribute__((address_space(3))) unsigned int*)lds, 16, 0, 0);
}

// ---------------- fp32 -> bf16 convert (8 elems/thread) ----------------
__global__ __launch_bounds__(256) void cvt_bf16_kernel(
    const float* __restrict__ in, unsigned short* __restrict__ out, int n) {
  int i = (blockIdx.x * 256 + threadIdx.x) * 8;
  if (i >= n) return;
  const float4 a = *(const float4*)(in + i);
  const float4 b = *(const float4*)(in + i + 4);
  short8 o;
  o[0] = (short)f2bf(a.x); o[1] = (short)f2bf(a.y);
  o[2] = (short)f2bf(a.z); o[3] = (short)f2bf(a.w);
  o[4] = (short)f2bf(b.x); o[5] = (short)f2bf(b.y);
  o[6] = (short)f2bf(b.z); o[7] = (short)f2bf(b.w);
  *(short8*)(out + i) = o;
}

// ------------- transpose fp32 (K x N) -> bf16 (N x K) ------------------
__global__ __launch_bounds__(256) void transpose_w_kernel(
    const float* __restrict__ in, unsigned short* __restrict__ out,
    int Kdim, int Ndim) {
  __shared__ float t[32][33];
  const int nb = blockIdx.x * 32, kb = blockIdx.y * 32;
  const int tx = threadIdx.x & 31, ty = threadIdx.x >> 5;  // ty 0..7
#pragma unroll
  for (int i = 0; i < 32; i += 8)
    t[ty + i][tx] = in[(size_t)(kb + ty + i) * Ndim + nb + tx];
  __syncthreads();
#pragma unroll
  for (int i = 0; i < 32; i += 8)
    out[(size_t)(nb + ty + i) * Kdim + kb + tx] = f2bf(t[tx][ty + i]);
}

// --------- transpose V (bh, s, 64) bf16 -> Vt (bh, 64, s) bf16 ---------
__global__ __launch_bounds__(256) void transpose_v_kernel(
    const unsigned short* __restrict__ V, unsigned short* __restrict__ Vt) {
  __shared__ __align__(16) unsigned short t[64][72];  // 144B row stride
  const int bh = blockIdx.y, s0 = blockIdx.x * 64;
  const int tid = threadIdx.x;
  const unsigned short* src = V + ((size_t)bh * 2048 + s0) * 64;
#pragma unroll
  for (int pass = 0; pass < 2; ++pass) {
    int r = (tid >> 3) + pass * 32;
    short8 v = *(const short8*)(src + r * 64 + (tid & 7) * 8);
    *(short8*)(&t[r][(tid & 7) * 8]) = v;
  }
  __syncthreads();
  unsigned short* dst = Vt + (size_t)bh * 64 * 2048 + s0;
#pragma unroll
  for (int pass = 0; pass < 2; ++pass) {
    int d = (tid >> 3) + pass * 32;
    int ss = (tid & 7) * 8;
    short8 v;
#pragma unroll
    for (int j = 0; j < 8; ++j) v[j] = (short)t[ss + j][d];
    *(short8*)(dst + (size_t)d * 2048 + ss) = v;
  }
}

// ---------------- GEMM: C(MxN) = A(MxK,bf16) * Bt(NxK,bf16)^T ----------
// MODE 0: scatter-epilogue into Q/K/V (b,h,s,d) bf16, Q scaled by 0.125
// MODE 1: fp32 C output, row-major MxN
template<int M, int N, int K, int MODE>
__global__ __launch_bounds__(256)
void gemm_bt_kernel(const unsigned short* __restrict__ A,
                    const unsigned short* __restrict__ Bt,
                    unsigned short* __restrict__ Qd,
                    unsigned short* __restrict__ Kd,
                    unsigned short* __restrict__ Vd,
                    float* __restrict__ outC) {
  __shared__ __align__(16) unsigned short lsA[128 * 32];
  __shared__ __align__(16) unsigned short lsB[128 * 32];
  const int tid = threadIdx.x, wid = tid >> 6, lane = tid & 63;
  const int wr = wid >> 1, wc = wid & 1;
  const int m0 = blockIdx.y * 128, n0 = blockIdx.x * 128;

  f32x4 acc[4][4] = {};

  const int rA = lane >> 2, kA = (lane & 3) * 8;
  for (int kt = 0; kt < K / 32; ++kt) {
    __syncthreads();  // previous tile fully consumed
#pragma unroll
    for (int c = 0; c < 2; ++c) {
      const int q = c * 4 + wid;  // wave-chunk id, 16 rows each
      gld16(A  + (size_t)(m0 + q * 16 + rA) * K + kt * 32 + kA, lsA + q * 512);
      gld16(Bt + (size_t)(n0 + q * 16 + rA) * K + kt * 32 + kA, lsB + q * 512);
    }
    __syncthreads();  // compiler drains vmcnt before barrier
    short8 af[4], bfr[4];
#pragma unroll
    for (int i = 0; i < 4; ++i) {
      af[i]  = *(const short8*)(lsA + (wr * 64 + i * 16 + (lane & 15)) * 32 + (lane >> 4) * 8);
      bfr[i] = *(const short8*)(lsB + (wc * 64 + i * 16 + (lane & 15)) * 32 + (lane >> 4) * 8);
    }
#pragma unroll
    for (int i = 0; i < 4; ++i)
#pragma unroll
      for (int j = 0; j < 4; ++j)
        acc[i][j] = __builtin_amdgcn_mfma_f32_16x16x32_bf16(af[i], bfr[j], acc[i][j], 0, 0, 0);
  }

#pragma unroll
  for (int i = 0; i < 4; ++i) {
#pragma unroll
    for (int j = 0; j < 4; ++j) {
      const int rbase = m0 + wr * 64 + i * 16 + (lane >> 4) * 4;
      const int col = n0 + wc * 64 + j * 16 + (lane & 15);
      if constexpr (MODE == 0) {
        const int which = col >> 10, h = (col >> 6) & 15, d = col & 63;
        unsigned short* dst = which == 0 ? Qd : (which == 1 ? Kd : Vd);
        const float scale = which == 0 ? 0.125f : 1.0f;  // exact 1/sqrt(64)
#pragma unroll
        for (int ii = 0; ii < 4; ++ii) {
          const int r = rbase + ii, b = r >> 11, s = r & 2047;
          dst[((size_t)(b * 16 + h) * 2048 + s) * 64 + d] = f2bf(acc[i][j][ii] * scale);
        }
      } else {
#pragma unroll
        for (int ii = 0; ii < 4; ++ii)
          outC[(size_t)(rbase + ii) * N + col] = acc[i][j][ii];
      }
    }
  }
}

// ---------------- causal flash attention ----------------
// grid (S/64, B*H), 4 waves, each wave owns 16 q rows. KV tile = 32.
// Q/K layout (bh, s, 64); V transposed (bh, 64, s). Out (b,s,h*64+d) bf16.
__global__ __launch_bounds__(256)
void attn_kernel(const unsigned short* __restrict__ Q,
                 const unsigned short* __restrict__ Kc,
                 const unsigned short* __restrict__ Vt,
                 unsigned short* __restrict__ O) {
  __shared__ __align__(16) unsigned short plds[4][512];  // per-wave P buffer
  const int bh = blockIdx.y;
  const int wid = threadIdx.x >> 6, lane = threadIdx.x & 63;
  const int q0 = blockIdx.x * 64 + wid * 16;

  const unsigned short* Qb = Q  + (size_t)bh * 2048 * 64;
  const unsigned short* Kb = Kc + (size_t)bh * 2048 * 64;
  const unsigned short* Vb = Vt + (size_t)bh * 64 * 2048;

  short8 qa[2];
#pragma unroll
  for (int ks = 0; ks < 2; ++ks)
    qa[ks] = *(const short8*)(Qb + (size_t)(q0 + (lane & 15)) * 64 + ks * 32 + (lane >> 4) * 8);

  f32x4 o[4] = {};
  float mrow[4] = {-INFINITY, -INFINITY, -INFINITY, -INFINITY};
  float lrow[4] = {0.f, 0.f, 0.f, 0.f};

  const int ntiles = (q0 + 47) >> 5;  // kv tiles with kv0 <= q0+15
  unsigned short* pw = plds[wid];

  for (int kt = 0; kt < ntiles; ++kt) {
    const int kv0 = kt * 32;
    f32x4 s[2] = {};
#pragma unroll
    for (int g = 0; g < 2; ++g)
#pragma unroll
      for (int ks = 0; ks < 2; ++ks) {
        const short8 kf = *(const short8*)(Kb + (size_t)(kv0 + g * 16 + (lane & 15)) * 64 + ks * 32 + (lane >> 4) * 8);
        s[g] = __builtin_amdgcn_mfma_f32_16x16x32_bf16(qa[ks], kf, s[g], 0, 0, 0);
      }
    if (kv0 + 31 > q0) {  // diagonal tile: apply causal mask
#pragma unroll
      for (int g = 0; g < 2; ++g)
#pragma unroll
        for (int i = 0; i < 4; ++i) {
          const int colk = kv0 + g * 16 + (lane & 15);
          const int rowq = q0 + (lane >> 4) * 4 + i;
          if (colk > rowq) s[g][i] = -INFINITY;
        }
    }
    float mt[4], psum[4];
#pragma unroll
    for (int i = 0; i < 4; ++i) mt[i] = fmaxf(s[0][i], s[1][i]);
    for (int off = 1; off < 16; off <<= 1)
#pragma unroll
      for (int i = 0; i < 4; ++i)
        mt[i] = fmaxf(mt[i], __shfl_xor(mt[i], off, 64));
    float mnew[4], alpha[4];
#pragma unroll
    for (int i = 0; i < 4; ++i) {
      mnew[i] = fmaxf(mrow[i], mt[i]);
      alpha[i] = __expf(mrow[i] - mnew[i]);  // 0 on first tile
    }
    f32x4 p[2];
#pragma unroll
    for (int g = 0; g < 2; ++g)
#pragma unroll
      for (int i = 0; i < 4; ++i)
        p[g][i] = __expf(s[g][i] - mnew[i]);  // masked -> exp(-inf)=0
#pragma unroll
    for (int i = 0; i < 4; ++i) psum[i] = p[0][i] + p[1][i];
    for (int off = 1; off < 16; off <<= 1)
#pragma unroll
      for (int i = 0; i < 4; ++i)
        psum[i] += __shfl_xor(psum[i], off, 64);
#pragma unroll
    for (int i = 0; i < 4; ++i) {
      lrow[i] = lrow[i] * alpha[i] + psum[i];
      mrow[i] = mnew[i];
    }
#pragma unroll
    for (int cg = 0; cg < 4; ++cg)
#pragma unroll
      for (int i = 0; i < 4; ++i)
        o[cg][i] *= alpha[i];
    // P (D-frag layout) -> LDS -> A-frag layout, bf16
#pragma unroll
    for (int g = 0; g < 2; ++g)
#pragma unroll
      for (int i = 0; i < 4; ++i)
        pw[((lane >> 4) * 4 + i) * 32 + g * 16 + (lane & 15)] = f2bf(p[g][i]);
    asm volatile("s_waitcnt lgkmcnt(0)" ::: "memory");  // cross-lane LDS visibility
    const short8 pa = *(const short8*)(pw + (lane & 15) * 32 + (lane >> 4) * 8);
    asm volatile("" ::: "memory");  // keep next iter's writes below this read
#pragma unroll
    for (int cg = 0; cg < 4; ++cg) {
      const short8 vf = *(const short8*)(Vb + (size_t)(cg * 16 + (lane & 15)) * 2048 + kv0 + (lane >> 4) * 8);
      o[cg] = __builtin_amdgcn_mfma_f32_16x16x32_bf16(pa, vf, o[cg], 0, 0, 0);
    }
  }

  const int b = bh >> 4, h = bh & 15;
#pragma unroll
  for (int i = 0; i < 4; ++i) {
    const float inv = 1.0f / lrow[i];
    const int r = q0 + (lane >> 4) * 4 + i;
#pragma unroll
    for (int cg = 0; cg < 4; ++cg) {
      const int d = cg * 16 + (lane & 15);
      O[((size_t)(b * 2048 + r)) * 1024 + h * 64 + d] = f2bf(o[cg][i] * inv);
    }
  }
}

extern "C" void kernel_launch(void* const* d_in, const int* in_sizes, int n_in,
                              void* d_out, int out_size, void* d_ws, size_t ws_size,
                              hipStream_t stream) {
  (void)in_sizes; (void)n_in; (void)out_size; (void)ws_size;
  const float* x      = (const float*)d_in[0];
  const float* w_qkv  = (const float*)d_in[1];
  const float* w_proj = (const float*)d_in[2];
  float* out = (float*)d_out;
  char* ws = (char*)d_ws;

  // workspace layout (bytes)
  unsigned short* x_bf   = (unsigned short*)(ws);              // 16 MB (reused as attn_out)
  unsigned short* wqT    = (unsigned short*)(ws + 16777216);   // 6 MB
  unsigned short* wpT    = (unsigned short*)(ws + 23068672);   // 2 MB
  unsigned short* Qd     = (unsigned short*)(ws + 25165824);   // 16 MB
  unsigned short* Kd     = (unsigned short*)(ws + 41943040);   // 16 MB
  unsigned short* Vd     = (unsigned short*)(ws + 58720256);   // 16 MB
  unsigned short* Vt     = (unsigned short*)(ws + 75497472);   // 16 MB
  unsigned short* attn_o = x_bf;                               // x_bf dead after GEMM1

  cvt_bf16_kernel<<<4096, 256, 0, stream>>>(x, x_bf, 8388608);
  transpose_w_kernel<<<dim3(96, 32), 256, 0, stream>>>(w_qkv, wqT, 1024, 3072);
  transpose_w_kernel<<<dim3(32, 32), 256, 0, stream>>>(w_proj, wpT, 1024, 1024);
  gemm_bt_kernel<8192, 3072, 1024, 0><<<dim3(24, 64), 256, 0, stream>>>(
      x_bf, wqT, Qd, Kd, Vd, nullptr);
  transpose_v_kernel<<<dim3(32, 64), 256, 0, stream>>>(Vd, Vt);
  attn_kernel<<<dim3(32, 64), 256, 0, stream>>>(Qd, Kd, Vt, attn_o);
  gemm_bt_kernel<8192, 1024, 1024, 1><<<dim3(8, 64), 256, 0, stream>>>(
      attn_o, wpT, nullptr, nullptr, nullptr, out);
}

// Round 2
// 342.134 us; speedup vs baseline: 1.6451x; 1.6451x over previous
//
#include <hip/hip_runtime.h>
#include <stdint.h>
#include <math.h>

typedef __attribute__((ext_vector_type(8))) short short8;
typedef __attribute__((ext_vector_type(4))) float f32x4;
typedef __attribute__((ext_vector_type(16))) float f32x16;

#define DEV __device__ __forceinline__

DEV unsigned short f2bf(float f) {
  union { float f; unsigned int u; } v; v.f = f;
  return (unsigned short)((v.u + 0x7FFFu + ((v.u >> 16) & 1u)) >> 16);
}

DEV unsigned int pkbf(float a, float b) {  // low16 = bf16(a), high16 = bf16(b)
  unsigned int r;
  asm("v_cvt_pk_bf16_f32 %0, %1, %2" : "=v"(r) : "v"(a), "v"(b));
  return r;
}

DEV void gld16(const void* g, void* lds) {
  __builtin_amdgcn_global_load_lds(
      (const __attribute__((address_space(1))) unsigned int*)g,
      (__attribute__((address_space(3))) unsigned int*)lds, 16, 0, 0);
}

// ---------------- fp32 -> bf16 convert (8 elems/thread) ----------------
__global__ __launch_bounds__(256) void cvt_bf16_kernel(
    const float* __restrict__ in, unsigned short* __restrict__ out, int n) {
  int i = (blockIdx.x * 256 + threadIdx.x) * 8;
  if (i >= n) return;
  const float4 a = *(const float4*)(in + i);
  const float4 b = *(const float4*)(in + i + 4);
  short8 o;
  o[0] = (short)f2bf(a.x); o[1] = (short)f2bf(a.y);
  o[2] = (short)f2bf(a.z); o[3] = (short)f2bf(a.w);
  o[4] = (short)f2bf(b.x); o[5] = (short)f2bf(b.y);
  o[6] = (short)f2bf(b.z); o[7] = (short)f2bf(b.w);
  *(short8*)(out + i) = o;
}

// ------------- transpose fp32 (K x N) -> bf16 (N x K) ------------------
__global__ __launch_bounds__(256) void transpose_w_kernel(
    const float* __restrict__ in, unsigned short* __restrict__ out,
    int Kdim, int Ndim) {
  __shared__ float t[32][33];
  const int nb = blockIdx.x * 32, kb = blockIdx.y * 32;
  const int tx = threadIdx.x & 31, ty = threadIdx.x >> 5;  // ty 0..7
#pragma unroll
  for (int i = 0; i < 32; i += 8)
    t[ty + i][tx] = in[(size_t)(kb + ty + i) * Ndim + nb + tx];
  __syncthreads();
#pragma unroll
  for (int i = 0; i < 32; i += 8)
    out[(size_t)(nb + ty + i) * Kdim + kb + tx] = f2bf(t[tx][ty + i]);
}

// --------- transpose V (bh, s, 64) bf16 -> Vt (bh, 64, s) bf16 ---------
__global__ __launch_bounds__(256) void transpose_v_kernel(
    const unsigned short* __restrict__ V, unsigned short* __restrict__ Vt) {
  __shared__ __align__(16) unsigned short t[64][72];
  const int bh = blockIdx.y, s0 = blockIdx.x * 64;
  const int tid = threadIdx.x;
  const unsigned short* src = V + ((size_t)bh * 2048 + s0) * 64;
#pragma unroll
  for (int pass = 0; pass < 2; ++pass) {
    int r = (tid >> 3) + pass * 32;
    short8 v = *(const short8*)(src + r * 64 + (tid & 7) * 8);
    *(short8*)(&t[r][(tid & 7) * 8]) = v;
  }
  __syncthreads();
  unsigned short* dst = Vt + (size_t)bh * 64 * 2048 + s0;
#pragma unroll
  for (int pass = 0; pass < 2; ++pass) {
    int d = (tid >> 3) + pass * 32;
    int ss = (tid & 7) * 8;
    short8 v;
#pragma unroll
    for (int j = 0; j < 8; ++j) v[j] = (short)t[ss + j][d];
    *(short8*)(dst + (size_t)d * 2048 + ss) = v;
  }
}

// ---------------- GEMM: C(MxN) = A(MxK,bf16) * Bt(NxK,bf16)^T ----------
template<int M, int N, int K, int MODE>
__global__ __launch_bounds__(256)
void gemm_bt_kernel(const unsigned short* __restrict__ A,
                    const unsigned short* __restrict__ Bt,
                    unsigned short* __restrict__ Qd,
                    unsigned short* __restrict__ Kd,
                    unsigned short* __restrict__ Vd,
                    float* __restrict__ outC) {
  __shared__ __align__(16) unsigned short lsA[128 * 32];
  __shared__ __align__(16) unsigned short lsB[128 * 32];
  const int tid = threadIdx.x, wid = tid >> 6, lane = tid & 63;
  const int wr = wid >> 1, wc = wid & 1;
  const int m0 = blockIdx.y * 128, n0 = blockIdx.x * 128;

  f32x4 acc[4][4] = {};

  const int rA = lane >> 2, kA = (lane & 3) * 8;
  for (int kt = 0; kt < K / 32; ++kt) {
    __syncthreads();
#pragma unroll
    for (int c = 0; c < 2; ++c) {
      const int q = c * 4 + wid;
      gld16(A  + (size_t)(m0 + q * 16 + rA) * K + kt * 32 + kA, lsA + q * 512);
      gld16(Bt + (size_t)(n0 + q * 16 + rA) * K + kt * 32 + kA, lsB + q * 512);
    }
    __syncthreads();
    short8 af[4], bfr[4];
#pragma unroll
    for (int i = 0; i < 4; ++i) {
      af[i]  = *(const short8*)(lsA + (wr * 64 + i * 16 + (lane & 15)) * 32 + (lane >> 4) * 8);
      bfr[i] = *(const short8*)(lsB + (wc * 64 + i * 16 + (lane & 15)) * 32 + (lane >> 4) * 8);
    }
#pragma unroll
    for (int i = 0; i < 4; ++i)
#pragma unroll
      for (int j = 0; j < 4; ++j)
        acc[i][j] = __builtin_amdgcn_mfma_f32_16x16x32_bf16(af[i], bfr[j], acc[i][j], 0, 0, 0);
  }

#pragma unroll
  for (int i = 0; i < 4; ++i) {
#pragma unroll
    for (int j = 0; j < 4; ++j) {
      const int rbase = m0 + wr * 64 + i * 16 + (lane >> 4) * 4;
      const int col = n0 + wc * 64 + j * 16 + (lane & 15);
      if constexpr (MODE == 0) {
        const int which = col >> 10, h = (col >> 6) & 15, d = col & 63;
        unsigned short* dst = which == 0 ? Qd : (which == 1 ? Kd : Vd);
        const float scale = which == 0 ? 0.125f : 1.0f;
#pragma unroll
        for (int ii = 0; ii < 4; ++ii) {
          const int r = rbase + ii, b = r >> 11, s = r & 2047;
          dst[((size_t)(b * 16 + h) * 2048 + s) * 64 + d] = f2bf(acc[i][j][ii] * scale);
        }
      } else {
#pragma unroll
        for (int ii = 0; ii < 4; ++ii)
          outC[(size_t)(rbase + ii) * N + col] = acc[i][j][ii];
      }
    }
  }
}

// ---------------- causal flash attention, swapped-QK^T, lane-local softmax ----
// grid (16, B*H), 4 waves/block, 32 q-rows per wave, KV tile = 32, no LDS.
// S^T = mfma(K_frag, Q_frag): lane owns q = q0 + (lane&31), 16 k-scores in regs.
// O kept transposed (O^T = mfma(Vt_frag, Pt_frag)): rescale/norm lane-local.
__global__ __launch_bounds__(256)
void attn_kernel(const unsigned short* __restrict__ Q,
                 const unsigned short* __restrict__ Kc,
                 const unsigned short* __restrict__ Vt,
                 unsigned short* __restrict__ O) {
  const int bh = blockIdx.y;
  const int wid = threadIdx.x >> 6, lane = threadIdx.x & 63;
  const int qb = gridDim.x - 1 - blockIdx.x;        // heavy blocks dispatch first
  const int q0 = qb * 128 + wid * 32;
  const int ql = lane & 31, h = lane >> 5;          // h: which k-half of the row pattern

  const unsigned short* Qb = Q  + (size_t)bh * 2048 * 64;
  const unsigned short* Kb = Kc + (size_t)bh * 2048 * 64;
  const unsigned short* Vb = Vt + (size_t)bh * 64 * 2048;

  // Q B-frag: lane holds Q[q0+ql][s*16 + h*8 .. +8]
  short8 qf[4];
#pragma unroll
  for (int s = 0; s < 4; ++s)
    qf[s] = *(const short8*)(Qb + (size_t)(q0 + ql) * 64 + s * 16 + h * 8);

  f32x16 o0 = {}, o1 = {};          // O^T accum: col q=ql, rows d (t*32 + pattern)
  float m = -INFINITY, l = 0.f;     // lane-local softmax state for q = q0+ql

  const int ntiles = (q0 >> 5) + 1;

  // preload K tile 0 (A-frag: lane holds K[kv0+ql][s*16 + h*8 .. +8])
  short8 kf[4];
#pragma unroll
  for (int s = 0; s < 4; ++s)
    kf[s] = *(const short8*)(Kb + (size_t)ql * 64 + s * 16 + h * 8);

  for (int kt = 0; kt < ntiles; ++kt) {
    const int kv0 = kt * 32;

    // S^T[k,q] accum over d=64 (4 chained 32x32x16)
    f32x16 st = {};
#pragma unroll
    for (int s = 0; s < 4; ++s)
      st = __builtin_amdgcn_mfma_f32_32x32x16_bf16(kf[s], qf[s], st, 0, 0, 0);

    // issue V loads early (consumed after softmax VALU block)
    short8 vf[4];
#pragma unroll
    for (int t = 0; t < 2; ++t)
#pragma unroll
      for (int s = 0; s < 2; ++s)
        vf[t * 2 + s] = *(const short8*)(Vb + (size_t)(t * 32 + ql) * 2048 + kv0 + s * 16 + h * 8);

    // prefetch next K tile (clamped; discarded on last iter)
    {
      int knext = kv0 + 32; if (knext > 2048 - 32) knext = 2048 - 32;
#pragma unroll
      for (int s = 0; s < 4; ++s)
        kf[s] = *(const short8*)(Kb + (size_t)(knext + ql) * 64 + s * 16 + h * 8);
    }

    // causal mask (wave-uniform branch: only the diagonal tile)
    if (kt == ntiles - 1) {
#pragma unroll
      for (int r = 0; r < 16; ++r) {
        const int krow = (r & 3) + 8 * (r >> 2) + 4 * h;
        if (kv0 + krow > q0 + ql) st[r] = -INFINITY;
      }
    }

    // lane-local softmax over this tile's 32 k (16 here + 16 in lane^32)
    float pm = st[0];
#pragma unroll
    for (int r = 1; r < 16; ++r) pm = fmaxf(pm, st[r]);
    pm = fmaxf(pm, __shfl_xor(pm, 32, 64));

    if (!__all(pm <= m + 8.f)) {    // defer-max (T13): rescale only on real growth
      const float mn = fmaxf(m, pm);
      const float alpha = __expf(m - mn);
      m = mn;
      l *= alpha;
#pragma unroll
      for (int r = 0; r < 16; ++r) { o0[r] *= alpha; o1[r] *= alpha; }
    }

    float p[16];
#pragma unroll
    for (int r = 0; r < 16; ++r) p[r] = __expf(st[r] - m);
    float ps = 0.f;
#pragma unroll
    for (int r = 0; r < 16; ++r) ps += p[r];
    ps += __shfl_xor(ps, 32, 64);
    l += ps;

    // P^T B-frag assembly: pack bf16 pairs, exchange halves with lane^32
    unsigned int w[8], x[8];
#pragma unroll
    for (int i = 0; i < 8; ++i) w[i] = pkbf(p[2 * i], p[2 * i + 1]);
#pragma unroll
    for (int i = 0; i < 8; ++i) x[i] = __shfl_xor(w[i], 32, 64);
    union { unsigned int u[4]; short8 s8; } f0, f1;
    f0.u[0] = h ? x[2] : w[0]; f0.u[1] = h ? x[3] : w[1];
    f0.u[2] = h ? w[2] : x[0]; f0.u[3] = h ? w[3] : x[1];
    f1.u[0] = h ? x[6] : w[4]; f1.u[1] = h ? x[7] : w[5];
    f1.u[2] = h ? w[6] : x[4]; f1.u[3] = h ? w[7] : x[5];

    // O^T += V^T * P^T   (two d-halves t, two k-slices s)
    o0 = __builtin_amdgcn_mfma_f32_32x32x16_bf16(vf[0], f0.s8, o0, 0, 0, 0);
    o0 = __builtin_amdgcn_mfma_f32_32x32x16_bf16(vf[1], f1.s8, o0, 0, 0, 0);
    o1 = __builtin_amdgcn_mfma_f32_32x32x16_bf16(vf[2], f0.s8, o1, 0, 0, 0);
    o1 = __builtin_amdgcn_mfma_f32_32x32x16_bf16(vf[3], f1.s8, o1, 0, 0, 0);
  }

  // epilogue: lane-local 1/l, store O[q][d] from O^T regs (4-wide d groups, 8B stores)
  const float inv = 1.0f / l;
  const int b = bh >> 4, head = bh & 15;
  unsigned short* Orow = O + ((size_t)(b * 2048 + q0 + ql)) * 1024 + head * 64;
#pragma unroll
  for (int g = 0; g < 4; ++g) {
    {
      const unsigned int lo = pkbf(o0[g * 4 + 0] * inv, o0[g * 4 + 1] * inv);
      const unsigned int hi = pkbf(o0[g * 4 + 2] * inv, o0[g * 4 + 3] * inv);
      uint2 val; val.x = lo; val.y = hi;
      *(uint2*)(Orow + 8 * g + 4 * h) = val;
    }
    {
      const unsigned int lo = pkbf(o1[g * 4 + 0] * inv, o1[g * 4 + 1] * inv);
      const unsigned int hi = pkbf(o1[g * 4 + 2] * inv, o1[g * 4 + 3] * inv);
      uint2 val; val.x = lo; val.y = hi;
      *(uint2*)(Orow + 32 + 8 * g + 4 * h) = val;
    }
  }
}

extern "C" void kernel_launch(void* const* d_in, const int* in_sizes, int n_in,
                              void* d_out, int out_size, void* d_ws, size_t ws_size,
                              hipStream_t stream) {
  (void)in_sizes; (void)n_in; (void)out_size; (void)ws_size;
  const float* x      = (const float*)d_in[0];
  const float* w_qkv  = (const float*)d_in[1];
  const float* w_proj = (const float*)d_in[2];
  float* out = (float*)d_out;
  char* ws = (char*)d_ws;

  unsigned short* x_bf   = (unsigned short*)(ws);              // 16 MB (reused as attn_out)
  unsigned short* wqT    = (unsigned short*)(ws + 16777216);   // 6 MB
  unsigned short* wpT    = (unsigned short*)(ws + 23068672);   // 2 MB
  unsigned short* Qd     = (unsigned short*)(ws + 25165824);   // 16 MB
  unsigned short* Kd     = (unsigned short*)(ws + 41943040);   // 16 MB
  unsigned short* Vd     = (unsigned short*)(ws + 58720256);   // 16 MB
  unsigned short* Vt     = (unsigned short*)(ws + 75497472);   // 16 MB
  unsigned short* attn_o = x_bf;

  cvt_bf16_kernel<<<4096, 256, 0, stream>>>(x, x_bf, 8388608);
  transpose_w_kernel<<<dim3(96, 32), 256, 0, stream>>>(w_qkv, wqT, 1024, 3072);
  transpose_w_kernel<<<dim3(32, 32), 256, 0, stream>>>(w_proj, wpT, 1024, 1024);
  gemm_bt_kernel<8192, 3072, 1024, 0><<<dim3(24, 64), 256, 0, stream>>>(
      x_bf, wqT, Qd, Kd, Vd, nullptr);
  transpose_v_kernel<<<dim3(32, 64), 256, 0, stream>>>(Vd, Vt);
  attn_kernel<<<dim3(16, 64), 256, 0, stream>>>(Qd, Kd, Vt, attn_o);
  gemm_bt_kernel<8192, 1024, 1024, 1><<<dim3(8, 64), 256, 0, stream>>>(
      attn_o, wpT, nullptr, nullptr, nullptr, out);
}

// Round 3
// 237.856 us; speedup vs baseline: 2.3663x; 1.4384x over previous
//
#include <hip/hip_runtime.h>
#include <stdint.h>
#include <math.h>

typedef __attribute__((ext_vector_type(8))) short short8;
typedef __attribute__((ext_vector_type(4))) float f32x4;
typedef __attribute__((ext_vector_type(16))) float f32x16;

#define DEV __device__ __forceinline__

DEV unsigned short f2bf(float f) {
  union { float f; unsigned int u; } v; v.f = f;
  return (unsigned short)((v.u + 0x7FFFu + ((v.u >> 16) & 1u)) >> 16);
}

DEV unsigned int pkbf(float a, float b) {  // low16 = bf16(a), high16 = bf16(b)
  unsigned int r;
  asm("v_cvt_pk_bf16_f32 %0, %1, %2" : "=v"(r) : "v"(a), "v"(b));
  return r;
}

// pair-exchange with lane^32: returns {x, y} with {x,y} = {own, other} per lane
// (orientation-independent use: reduce with commutative op on both)
#if __has_builtin(__builtin_amdgcn_permlane32_swap)
DEV float redmax32(float v) {
  typedef __attribute__((ext_vector_type(2))) unsigned int uint2v;
  union { float f; unsigned int u; } c; c.f = v;
  uint2v r = __builtin_amdgcn_permlane32_swap(c.u, c.u, false, false);
  union { unsigned int u; float f; } a, b; a.u = r[0]; b.u = r[1];
  return fmaxf(a.f, b.f);
}
DEV float redsum32(float v) {
  typedef __attribute__((ext_vector_type(2))) unsigned int uint2v;
  union { float f; unsigned int u; } c; c.f = v;
  uint2v r = __builtin_amdgcn_permlane32_swap(c.u, c.u, false, false);
  union { unsigned int u; float f; } a, b; a.u = r[0]; b.u = r[1];
  return a.f + b.f;
}
#else
DEV float redmax32(float v) { return fmaxf(v, __shfl_xor(v, 32, 64)); }
DEV float redsum32(float v) { return v + __shfl_xor(v, 32, 64); }
#endif

DEV void gld16(const void* g, void* lds) {
  __builtin_amdgcn_global_load_lds(
      (const __attribute__((address_space(1))) unsigned int*)g,
      (__attribute__((address_space(3))) unsigned int*)lds, 16, 0, 0);
}

// ---------------- fp32 -> bf16 convert (8 elems/thread) ----------------
__global__ __launch_bounds__(256) void cvt_bf16_kernel(
    const float* __restrict__ in, unsigned short* __restrict__ out, int n) {
  int i = (blockIdx.x * 256 + threadIdx.x) * 8;
  if (i >= n) return;
  const float4 a = *(const float4*)(in + i);
  const float4 b = *(const float4*)(in + i + 4);
  short8 o;
  o[0] = (short)f2bf(a.x); o[1] = (short)f2bf(a.y);
  o[2] = (short)f2bf(a.z); o[3] = (short)f2bf(a.w);
  o[4] = (short)f2bf(b.x); o[5] = (short)f2bf(b.y);
  o[6] = (short)f2bf(b.z); o[7] = (short)f2bf(b.w);
  *(short8*)(out + i) = o;
}

// ------------- transpose fp32 (K x N) -> bf16 (N x K) ------------------
__global__ __launch_bounds__(256) void transpose_w_kernel(
    const float* __restrict__ in, unsigned short* __restrict__ out,
    int Kdim, int Ndim) {
  __shared__ float t[32][33];
  const int nb = blockIdx.x * 32, kb = blockIdx.y * 32;
  const int tx = threadIdx.x & 31, ty = threadIdx.x >> 5;  // ty 0..7
#pragma unroll
  for (int i = 0; i < 32; i += 8)
    t[ty + i][tx] = in[(size_t)(kb + ty + i) * Ndim + nb + tx];
  __syncthreads();
#pragma unroll
  for (int i = 0; i < 32; i += 8)
    out[(size_t)(nb + ty + i) * Kdim + kb + tx] = f2bf(t[tx][ty + i]);
}

// --------- transpose V (bh, s, 64) bf16 -> Vts (bh, 64, s') bf16 -------
// s' applies perm16 = swap bits 2,3 of (s mod 16) so that PV B-fragments
// are direct packs of the S^T D-fragment (no cross-lane exchange needed).
__global__ __launch_bounds__(256) void transpose_v_kernel(
    const unsigned short* __restrict__ V, unsigned short* __restrict__ Vt) {
  __shared__ __align__(16) unsigned short t[64][72];
  const int bh = blockIdx.y, s0 = blockIdx.x * 64;
  const int tid = threadIdx.x;
  const unsigned short* src = V + ((size_t)bh * 2048 + s0) * 64;
#pragma unroll
  for (int pass = 0; pass < 2; ++pass) {
    int r = (tid >> 3) + pass * 32;
    short8 v = *(const short8*)(src + r * 64 + (tid & 7) * 8);
    *(short8*)(&t[r][(tid & 7) * 8]) = v;
  }
  __syncthreads();
  unsigned short* dst = Vt + (size_t)bh * 64 * 2048 + s0;
#pragma unroll
  for (int pass = 0; pass < 2; ++pass) {
    int d = (tid >> 3) + pass * 32;
    int ss = (tid & 7) * 8;
    short8 v;
#pragma unroll
    for (int j = 0; j < 8; ++j) {
      const int u = ss + j;
      const int g = (u & ~12) | ((u & 4) << 1) | ((u & 8) >> 1);  // swap bits 2,3
      v[j] = (short)t[g][d];
    }
    *(short8*)(dst + (size_t)d * 2048 + ss) = v;
  }
}

// ---------------- GEMM: C(MxN) = A(MxK,bf16) * Bt(NxK,bf16)^T ----------
template<int M, int N, int K, int MODE>
__global__ __launch_bounds__(256)
void gemm_bt_kernel(const unsigned short* __restrict__ A,
                    const unsigned short* __restrict__ Bt,
                    unsigned short* __restrict__ Qd,
                    unsigned short* __restrict__ Kd,
                    unsigned short* __restrict__ Vd,
                    float* __restrict__ outC) {
  __shared__ __align__(16) unsigned short lsA[128 * 32];
  __shared__ __align__(16) unsigned short lsB[128 * 32];
  const int tid = threadIdx.x, wid = tid >> 6, lane = tid & 63;
  const int wr = wid >> 1, wc = wid & 1;
  const int m0 = blockIdx.y * 128, n0 = blockIdx.x * 128;

  f32x4 acc[4][4] = {};

  const int rA = lane >> 2, kA = (lane & 3) * 8;
  for (int kt = 0; kt < K / 32; ++kt) {
    __syncthreads();
#pragma unroll
    for (int c = 0; c < 2; ++c) {
      const int q = c * 4 + wid;
      gld16(A  + (size_t)(m0 + q * 16 + rA) * K + kt * 32 + kA, lsA + q * 512);
      gld16(Bt + (size_t)(n0 + q * 16 + rA) * K + kt * 32 + kA, lsB + q * 512);
    }
    __syncthreads();
    short8 af[4], bfr[4];
#pragma unroll
    for (int i = 0; i < 4; ++i) {
      af[i]  = *(const short8*)(lsA + (wr * 64 + i * 16 + (lane & 15)) * 32 + (lane >> 4) * 8);
      bfr[i] = *(const short8*)(lsB + (wc * 64 + i * 16 + (lane & 15)) * 32 + (lane >> 4) * 8);
    }
#pragma unroll
    for (int i = 0; i < 4; ++i)
#pragma unroll
      for (int j = 0; j < 4; ++j)
        acc[i][j] = __builtin_amdgcn_mfma_f32_16x16x32_bf16(af[i], bfr[j], acc[i][j], 0, 0, 0);
  }

#pragma unroll
  for (int i = 0; i < 4; ++i) {
#pragma unroll
    for (int j = 0; j < 4; ++j) {
      const int rbase = m0 + wr * 64 + i * 16 + (lane >> 4) * 4;
      const int col = n0 + wc * 64 + j * 16 + (lane & 15);
      if constexpr (MODE == 0) {
        const int which = col >> 10, h = (col >> 6) & 15, d = col & 63;
        unsigned short* dst = which == 0 ? Qd : (which == 1 ? Kd : Vd);
        // Q pre-scaled by rsqrt(hd)*log2(e) so attention uses exp2 directly
        const float scale = which == 0 ? 0.18033688f : 1.0f;
#pragma unroll
        for (int ii = 0; ii < 4; ++ii) {
          const int r = rbase + ii, b = r >> 11, s = r & 2047;
          dst[((size_t)(b * 16 + h) * 2048 + s) * 64 + d] = f2bf(acc[i][j][ii] * scale);
        }
      } else {
#pragma unroll
        for (int ii = 0; ii < 4; ++ii)
          outC[(size_t)(rbase + ii) * N + col] = acc[i][j][ii];
      }
    }
  }
}

// ---------------- causal flash attention, paired q-tiles ----------------
// grid (8, B*H), 4 waves. Wave owns q-tiles qtA = bx*4+wid and qtB = 63-qtA:
// trip counts (qtA+1)+(qtB+1) = 65, uniform across ALL waves (no drain tail).
// Both parts share K/V fragments. Per-tile barrier keeps the block's 4 waves
// on the same kv tile -> L1 serves the 3 duplicate K/V streams.
// S^T = mfma(K,Q): lane owns q = q0+(lane&31); softmax fully lane-local
// (pair-exchange via permlane32_swap). V stored perm16-interleaved so the
// PV B-frag is a direct pack of p[0..7]/p[8..15] -- zero cross-lane ops.
__global__ __launch_bounds__(256, 2)
void attn_kernel(const unsigned short* __restrict__ Q,
                 const unsigned short* __restrict__ Kc,
                 const unsigned short* __restrict__ Vts,
                 unsigned short* __restrict__ O) {
  const int bh = blockIdx.y;
  const int wid = threadIdx.x >> 6, lane = threadIdx.x & 63;
  const int ql = lane & 31, h = lane >> 5;
  const int qtA = blockIdx.x * 4 + wid;      // 0..31
  const int qtB = 63 - qtA;                  // 32..63
  const int q0[2] = {qtA * 32, qtB * 32};
  const int lim[2] = {qtA + 1, qtB + 1};
  const int nwalk = 64 - blockIdx.x * 4;     // block-uniform loop count

  const unsigned short* Qb = Q   + (size_t)bh * 2048 * 64;
  const unsigned short* Kb = Kc  + (size_t)bh * 2048 * 64;
  const unsigned short* Vb = Vts + (size_t)bh * 64 * 2048;

  short8 qf[2][4];
#pragma unroll
  for (int pp = 0; pp < 2; ++pp)
#pragma unroll
    for (int s = 0; s < 4; ++s)
      qf[pp][s] = *(const short8*)(Qb + (size_t)(q0[pp] + ql) * 64 + s * 16 + h * 8);

  f32x16 o[2][2] = {};               // [part][d-half], O^T: col q, rows d
  float m[2] = {-INFINITY, -INFINITY};
  float l[2] = {0.f, 0.f};

  // preload K tile 0
  short8 kf[4];
#pragma unroll
  for (int s = 0; s < 4; ++s)
    kf[s] = *(const short8*)(Kb + (size_t)ql * 64 + s * 16 + h * 8);

  for (int t = 0; t < nwalk; ++t) {
    __syncthreads();                 // lockstep for L1 K/V sharing
    const int kv0 = t * 32;

    // V loads for this tile (consumed after softmax)
    short8 vf[4];
#pragma unroll
    for (int t2 = 0; t2 < 2; ++t2)
#pragma unroll
      for (int sl = 0; sl < 2; ++sl)
        vf[t2 * 2 + sl] = *(const short8*)(Vb + (size_t)(t2 * 32 + ql) * 2048 + kv0 + sl * 16 + h * 8);

    // prefetch next K tile
    short8 kn[4];
    {
      int knext = kv0 + 32; if (knext > 2048 - 32) knext = 2048 - 32;
#pragma unroll
      for (int s = 0; s < 4; ++s)
        kn[s] = *(const short8*)(Kb + (size_t)(knext + ql) * 64 + s * 16 + h * 8);
    }

#pragma unroll
    for (int pp = 0; pp < 2; ++pp) {
      if (t >= lim[pp]) continue;    // wave-uniform branch

      f32x16 st = {};
#pragma unroll
      for (int s = 0; s < 4; ++s)
        st = __builtin_amdgcn_mfma_f32_32x32x16_bf16(kf[s], qf[pp][s], st, 0, 0, 0);

      if (t == lim[pp] - 1) {        // diagonal tile: causal mask
#pragma unroll
        for (int r = 0; r < 16; ++r) {
          const int krow = (r & 3) + 8 * (r >> 2) + 4 * h;
          if (kv0 + krow > q0[pp] + ql) st[r] = -INFINITY;
        }
      }

      // lane-local max over 16, pair-exchange for full 32
      float pm = fmaxf(fmaxf(fmaxf(st[0], st[1]), fmaxf(st[2], st[3])),
                       fmaxf(fmaxf(st[4], st[5]), fmaxf(st[6], st[7])));
      pm = fmaxf(pm, fmaxf(fmaxf(fmaxf(st[8], st[9]), fmaxf(st[10], st[11])),
                           fmaxf(fmaxf(st[12], st[13]), fmaxf(st[14], st[15]))));
      pm = redmax32(pm);

      if (!__all(pm <= m[pp] + 11.5f)) {   // defer-max (log2 units)
        const float mn = fmaxf(m[pp], pm);
        const float al = exp2f(m[pp] - mn);
        m[pp] = mn;
        l[pp] *= al;
#pragma unroll
        for (int r = 0; r < 16; ++r) { o[pp][0][r] *= al; o[pp][1][r] *= al; }
      }

      float p[16];
#pragma unroll
      for (int r = 0; r < 16; ++r) p[r] = exp2f(st[r] - m[pp]);
      float ps = ((p[0] + p[1]) + (p[2] + p[3])) + ((p[4] + p[5]) + (p[6] + p[7]));
      ps += ((p[8] + p[9]) + (p[10] + p[11])) + ((p[12] + p[13]) + (p[14] + p[15]));
      l[pp] += redsum32(ps);

      // PV B-frags: direct packs (V is perm16-interleaved in memory)
      union { unsigned int u[4]; short8 s8; } f0, f1;
#pragma unroll
      for (int i = 0; i < 4; ++i) {
        f0.u[i] = pkbf(p[2 * i], p[2 * i + 1]);
        f1.u[i] = pkbf(p[8 + 2 * i], p[9 + 2 * i]);
      }
      o[pp][0] = __builtin_amdgcn_mfma_f32_32x32x16_bf16(vf[0], f0.s8, o[pp][0], 0, 0, 0);
      o[pp][0] = __builtin_amdgcn_mfma_f32_32x32x16_bf16(vf[1], f1.s8, o[pp][0], 0, 0, 0);
      o[pp][1] = __builtin_amdgcn_mfma_f32_32x32x16_bf16(vf[2], f0.s8, o[pp][1], 0, 0, 0);
      o[pp][1] = __builtin_amdgcn_mfma_f32_32x32x16_bf16(vf[3], f1.s8, o[pp][1], 0, 0, 0);
    }

#pragma unroll
    for (int s = 0; s < 4; ++s) kf[s] = kn[s];
  }

  // epilogue: lane-local 1/l, store both parts
  const int b = bh >> 4, head = bh & 15;
#pragma unroll
  for (int pp = 0; pp < 2; ++pp) {
    const float inv = 1.0f / l[pp];
    unsigned short* Orow = O + ((size_t)(b * 2048 + q0[pp] + ql)) * 1024 + head * 64;
#pragma unroll
    for (int g = 0; g < 4; ++g) {
      {
        const unsigned int lo = pkbf(o[pp][0][g * 4 + 0] * inv, o[pp][0][g * 4 + 1] * inv);
        const unsigned int hi = pkbf(o[pp][0][g * 4 + 2] * inv, o[pp][0][g * 4 + 3] * inv);
        uint2 val; val.x = lo; val.y = hi;
        *(uint2*)(Orow + 8 * g + 4 * h) = val;
      }
      {
        const unsigned int lo = pkbf(o[pp][1][g * 4 + 0] * inv, o[pp][1][g * 4 + 1] * inv);
        const unsigned int hi = pkbf(o[pp][1][g * 4 + 2] * inv, o[pp][1][g * 4 + 3] * inv);
        uint2 val; val.x = lo; val.y = hi;
        *(uint2*)(Orow + 32 + 8 * g + 4 * h) = val;
      }
    }
  }
}

extern "C" void kernel_launch(void* const* d_in, const int* in_sizes, int n_in,
                              void* d_out, int out_size, void* d_ws, size_t ws_size,
                              hipStream_t stream) {
  (void)in_sizes; (void)n_in; (void)out_size; (void)ws_size;
  const float* x      = (const float*)d_in[0];
  const float* w_qkv  = (const float*)d_in[1];
  const float* w_proj = (const float*)d_in[2];
  float* out = (float*)d_out;
  char* ws = (char*)d_ws;

  unsigned short* x_bf   = (unsigned short*)(ws);              // 16 MB (reused as attn_out)
  unsigned short* wqT    = (unsigned short*)(ws + 16777216);   // 6 MB
  unsigned short* wpT    = (unsigned short*)(ws + 23068672);   // 2 MB
  unsigned short* Qd     = (unsigned short*)(ws + 25165824);   // 16 MB
  unsigned short* Kd     = (unsigned short*)(ws + 41943040);   // 16 MB
  unsigned short* Vd     = (unsigned short*)(ws + 58720256);   // 16 MB
  unsigned short* Vt     = (unsigned short*)(ws + 75497472);   // 16 MB
  unsigned short* attn_o = x_bf;

  cvt_bf16_kernel<<<4096, 256, 0, stream>>>(x, x_bf, 8388608);
  transpose_w_kernel<<<dim3(96, 32), 256, 0, stream>>>(w_qkv, wqT, 1024, 3072);
  transpose_w_kernel<<<dim3(32, 32), 256, 0, stream>>>(w_proj, wpT, 1024, 1024);
  gemm_bt_kernel<8192, 3072, 1024, 0><<<dim3(24, 64), 256, 0, stream>>>(
      x_bf, wqT, Qd, Kd, Vd, nullptr);
  transpose_v_kernel<<<dim3(32, 64), 256, 0, stream>>>(Vd, Vt);
  attn_kernel<<<dim3(8, 64), 256, 0, stream>>>(Qd, Kd, Vt, attn_o);
  gemm_bt_kernel<8192, 1024, 1024, 1><<<dim3(8, 64), 256, 0, stream>>>(
      attn_o, wpT, nullptr, nullptr, nullptr, out);
}

// Round 5
// 225.443 us; speedup vs baseline: 2.4966x; 1.0551x over previous
//
#include <hip/hip_runtime.h>
#include <stdint.h>
#include <math.h>

typedef __attribute__((ext_vector_type(8))) short short8;
typedef __attribute__((ext_vector_type(4))) float f32x4;
typedef __attribute__((ext_vector_type(16))) float f32x16;

#define DEV __device__ __forceinline__

DEV unsigned short f2bf(float f) {
  union { float f; unsigned int u; } v; v.f = f;
  return (unsigned short)((v.u + 0x7FFFu + ((v.u >> 16) & 1u)) >> 16);
}

DEV unsigned int pkbf(float a, float b) {  // low16 = bf16(a), high16 = bf16(b)
  unsigned int r;
  asm("v_cvt_pk_bf16_f32 %0, %1, %2" : "=v"(r) : "v"(a), "v"(b));
  return r;
}

#if __has_builtin(__builtin_amdgcn_permlane32_swap)
DEV float redmax32(float v) {
  typedef __attribute__((ext_vector_type(2))) unsigned int uint2v;
  union { float f; unsigned int u; } c; c.f = v;
  uint2v r = __builtin_amdgcn_permlane32_swap(c.u, c.u, false, false);
  union { unsigned int u; float f; } a, b; a.u = r[0]; b.u = r[1];
  return fmaxf(a.f, b.f);
}
DEV float redsum32(float v) {
  typedef __attribute__((ext_vector_type(2))) unsigned int uint2v;
  union { float f; unsigned int u; } c; c.f = v;
  uint2v r = __builtin_amdgcn_permlane32_swap(c.u, c.u, false, false);
  union { unsigned int u; float f; } a, b; a.u = r[0]; b.u = r[1];
  return a.f + b.f;
}
#else
DEV float redmax32(float v) { return fmaxf(v, __shfl_xor(v, 32, 64)); }
DEV float redsum32(float v) { return v + __shfl_xor(v, 32, 64); }
#endif

DEV void gld16(const void* g, void* lds) {
  __builtin_amdgcn_global_load_lds(
      (const __attribute__((address_space(1))) unsigned int*)g,
      (__attribute__((address_space(3))) unsigned int*)lds, 16, 0, 0);
}

// ---------------- fp32 -> bf16 convert (8 elems/thread) ----------------
__global__ __launch_bounds__(256) void cvt_bf16_kernel(
    const float* __restrict__ in, unsigned short* __restrict__ out, int n) {
  int i = (blockIdx.x * 256 + threadIdx.x) * 8;
  if (i >= n) return;
  const float4 a = *(const float4*)(in + i);
  const float4 b = *(const float4*)(in + i + 4);
  short8 o;
  o[0] = (short)f2bf(a.x); o[1] = (short)f2bf(a.y);
  o[2] = (short)f2bf(a.z); o[3] = (short)f2bf(a.w);
  o[4] = (short)f2bf(b.x); o[5] = (short)f2bf(b.y);
  o[6] = (short)f2bf(b.z); o[7] = (short)f2bf(b.w);
  *(short8*)(out + i) = o;
}

// ------------- transpose fp32 (K x N) -> bf16 (N x K) ------------------
__global__ __launch_bounds__(256) void transpose_w_kernel(
    const float* __restrict__ in, unsigned short* __restrict__ out,
    int Kdim, int Ndim) {
  __shared__ float t[32][33];
  const int nb = blockIdx.x * 32, kb = blockIdx.y * 32;
  const int tx = threadIdx.x & 31, ty = threadIdx.x >> 5;  // ty 0..7
#pragma unroll
  for (int i = 0; i < 32; i += 8)
    t[ty + i][tx] = in[(size_t)(kb + ty + i) * Ndim + nb + tx];
  __syncthreads();
#pragma unroll
  for (int i = 0; i < 32; i += 8)
    out[(size_t)(nb + ty + i) * Kdim + kb + tx] = f2bf(t[tx][ty + i]);
}

// --------- transpose V (bh, s, 64) bf16 -> Vts (bh, 64, s') bf16 -------
// s' applies perm16 = swap bits 2,3 of (s mod 16) so that PV B-fragments
// are direct packs of the S^T D-fragment (no cross-lane exchange needed).
__global__ __launch_bounds__(256) void transpose_v_kernel(
    const unsigned short* __restrict__ V, unsigned short* __restrict__ Vt) {
  __shared__ __align__(16) unsigned short t[64][72];
  const int bh = blockIdx.y, s0 = blockIdx.x * 64;
  const int tid = threadIdx.x;
  const unsigned short* src = V + ((size_t)bh * 2048 + s0) * 64;
#pragma unroll
  for (int pass = 0; pass < 2; ++pass) {
    int r = (tid >> 3) + pass * 32;
    short8 v = *(const short8*)(src + r * 64 + (tid & 7) * 8);
    *(short8*)(&t[r][(tid & 7) * 8]) = v;
  }
  __syncthreads();
  unsigned short* dst = Vt + (size_t)bh * 64 * 2048 + s0;
#pragma unroll
  for (int pass = 0; pass < 2; ++pass) {
    int d = (tid >> 3) + pass * 32;
    int ss = (tid & 7) * 8;
    short8 v;
#pragma unroll
    for (int j = 0; j < 8; ++j) {
      const int u = ss + j;
      const int g = (u & ~12) | ((u & 4) << 1) | ((u & 8) >> 1);  // swap bits 2,3
      v[j] = (short)t[g][d];
    }
    *(short8*)(dst + (size_t)d * 2048 + ss) = v;
  }
}

// ---------------- GEMM: C(MxN) = A(MxK,bf16) * Bt(NxK,bf16)^T ----------
template<int M, int N, int K, int MODE>
__global__ __launch_bounds__(256)
void gemm_bt_kernel(const unsigned short* __restrict__ A,
                    const unsigned short* __restrict__ Bt,
                    unsigned short* __restrict__ Qd,
                    unsigned short* __restrict__ Kd,
                    unsigned short* __restrict__ Vd,
                    float* __restrict__ outC) {
  __shared__ __align__(16) unsigned short lsA[128 * 32];
  __shared__ __align__(16) unsigned short lsB[128 * 32];
  const int tid = threadIdx.x, wid = tid >> 6, lane = tid & 63;
  const int wr = wid >> 1, wc = wid & 1;
  const int m0 = blockIdx.y * 128, n0 = blockIdx.x * 128;

  f32x4 acc[4][4] = {};

  const int rA = lane >> 2, kA = (lane & 3) * 8;
  for (int kt = 0; kt < K / 32; ++kt) {
    __syncthreads();
#pragma unroll
    for (int c = 0; c < 2; ++c) {
      const int q = c * 4 + wid;
      gld16(A  + (size_t)(m0 + q * 16 + rA) * K + kt * 32 + kA, lsA + q * 512);
      gld16(Bt + (size_t)(n0 + q * 16 + rA) * K + kt * 32 + kA, lsB + q * 512);
    }
    __syncthreads();
    short8 af[4], bfr[4];
#pragma unroll
    for (int i = 0; i < 4; ++i) {
      af[i]  = *(const short8*)(lsA + (wr * 64 + i * 16 + (lane & 15)) * 32 + (lane >> 4) * 8);
      bfr[i] = *(const short8*)(lsB + (wc * 64 + i * 16 + (lane & 15)) * 32 + (lane >> 4) * 8);
    }
#pragma unroll
    for (int i = 0; i < 4; ++i)
#pragma unroll
      for (int j = 0; j < 4; ++j)
        acc[i][j] = __builtin_amdgcn_mfma_f32_16x16x32_bf16(af[i], bfr[j], acc[i][j], 0, 0, 0);
  }

#pragma unroll
  for (int i = 0; i < 4; ++i) {
#pragma unroll
    for (int j = 0; j < 4; ++j) {
      const int rbase = m0 + wr * 64 + i * 16 + (lane >> 4) * 4;
      const int col = n0 + wc * 64 + j * 16 + (lane & 15);
      if constexpr (MODE == 0) {
        const int which = col >> 10, h = (col >> 6) & 15, d = col & 63;
        unsigned short* dst = which == 0 ? Qd : (which == 1 ? Kd : Vd);
        // Q pre-scaled by rsqrt(hd)*log2(e) so attention uses exp2 directly
        const float scale = which == 0 ? 0.18033688f : 1.0f;
#pragma unroll
        for (int ii = 0; ii < 4; ++ii) {
          const int r = rbase + ii, b = r >> 11, s = r & 2047;
          dst[((size_t)(b * 16 + h) * 2048 + s) * 64 + d] = f2bf(acc[i][j][ii] * scale);
        }
      } else {
#pragma unroll
        for (int ii = 0; ii < 4; ++ii)
          outC[(size_t)(rbase + ii) * N + col] = acc[i][j][ii];
      }
    }
  }
}

// ---------------- causal flash attention, paired q-tiles ----------------
// ROUND 3 STRUCTURE VERBATIM (barrier in loop, in-loop V loads, K-only
// prefetch, block-uniform nwalk). Only change: 1-D grid with XCD-swizzled
// decode. bh = id & 63, walker w = id >> 6. Round-robin XCD assignment puts
// all 8 walkers of a bh on XCD bh%8 (64*w ≡ 0 mod 8): 8 bh per XCD ->
// K+V working set 4 MB = L2-resident. Walker 0 (heaviest) dispatches first.
// Wave wid owns q-tiles qtA = w*4+wid (0..31) and qtB = 63-qtA: 65
// tile-parts per wave, uniform. S^T = mfma(K,Q): lane owns q = q0+(lane&31);
// softmax fully lane-local (permlane32_swap pair-exchange). V stored
// perm16-interleaved so PV B-frag is a direct pack of p[] -- no cross-lane.
__global__ __launch_bounds__(256, 2)
void attn_kernel(const unsigned short* __restrict__ Q,
                 const unsigned short* __restrict__ Kc,
                 const unsigned short* __restrict__ Vts,
                 unsigned short* __restrict__ O) {
  const int bh = blockIdx.x & 63;
  const int w  = blockIdx.x >> 6;            // 0..7, walker 0 = heaviest
  const int wid = threadIdx.x >> 6, lane = threadIdx.x & 63;
  const int ql = lane & 31, h = lane >> 5;
  const int qtA = w * 4 + wid;               // 0..31
  const int qtB = 63 - qtA;                  // 32..63
  const int q0[2] = {qtA * 32, qtB * 32};
  const int lim[2] = {qtA + 1, qtB + 1};
  const int nwalk = 64 - w * 4;              // block-uniform loop count

  const unsigned short* Qb = Q   + (size_t)bh * 2048 * 64;
  const unsigned short* Kb = Kc  + (size_t)bh * 2048 * 64;
  const unsigned short* Vb = Vts + (size_t)bh * 64 * 2048;

  short8 qf[2][4];
#pragma unroll
  for (int pp = 0; pp < 2; ++pp)
#pragma unroll
    for (int s = 0; s < 4; ++s)
      qf[pp][s] = *(const short8*)(Qb + (size_t)(q0[pp] + ql) * 64 + s * 16 + h * 8);

  f32x16 o[2][2] = {};               // [part][d-half], O^T: col q, rows d
  float m[2] = {-INFINITY, -INFINITY};
  float l[2] = {0.f, 0.f};

  // preload K tile 0
  short8 kf[4];
#pragma unroll
  for (int s = 0; s < 4; ++s)
    kf[s] = *(const short8*)(Kb + (size_t)ql * 64 + s * 16 + h * 8);

  for (int t = 0; t < nwalk; ++t) {
    __syncthreads();                 // lockstep for L1/L2 K/V sharing
    const int kv0 = t * 32;

    // V loads for this tile (consumed after softmax)
    short8 vf[4];
#pragma unroll
    for (int t2 = 0; t2 < 2; ++t2)
#pragma unroll
      for (int sl = 0; sl < 2; ++sl)
        vf[t2 * 2 + sl] = *(const short8*)(Vb + (size_t)(t2 * 32 + ql) * 2048 + kv0 + sl * 16 + h * 8);

    // prefetch next K tile
    short8 kn[4];
    {
      int knext = kv0 + 32; if (knext > 2048 - 32) knext = 2048 - 32;
#pragma unroll
      for (int s = 0; s < 4; ++s)
        kn[s] = *(const short8*)(Kb + (size_t)(knext + ql) * 64 + s * 16 + h * 8);
    }

#pragma unroll
    for (int pp = 0; pp < 2; ++pp) {
      if (t >= lim[pp]) continue;    // wave-uniform branch

      f32x16 st = {};
#pragma unroll
      for (int s = 0; s < 4; ++s)
        st = __builtin_amdgcn_mfma_f32_32x32x16_bf16(kf[s], qf[pp][s], st, 0, 0, 0);

      if (t == lim[pp] - 1) {        // diagonal tile: causal mask
#pragma unroll
        for (int r = 0; r < 16; ++r) {
          const int krow = (r & 3) + 8 * (r >> 2) + 4 * h;
          if (kv0 + krow > q0[pp] + ql) st[r] = -INFINITY;
        }
      }

      // lane-local max over 16, pair-exchange for full 32
      float pm = fmaxf(fmaxf(fmaxf(st[0], st[1]), fmaxf(st[2], st[3])),
                       fmaxf(fmaxf(st[4], st[5]), fmaxf(st[6], st[7])));
      pm = fmaxf(pm, fmaxf(fmaxf(fmaxf(st[8], st[9]), fmaxf(st[10], st[11])),
                           fmaxf(fmaxf(st[12], st[13]), fmaxf(st[14], st[15]))));
      pm = redmax32(pm);

      if (!__all(pm <= m[pp] + 11.5f)) {   // defer-max (log2 units)
        const float mn = fmaxf(m[pp], pm);
        const float al = exp2f(m[pp] - mn);
        m[pp] = mn;
        l[pp] *= al;
#pragma unroll
        for (int r = 0; r < 16; ++r) { o[pp][0][r] *= al; o[pp][1][r] *= al; }
      }

      float p[16];
#pragma unroll
      for (int r = 0; r < 16; ++r) p[r] = exp2f(st[r] - m[pp]);
      float ps = ((p[0] + p[1]) + (p[2] + p[3])) + ((p[4] + p[5]) + (p[6] + p[7]));
      ps += ((p[8] + p[9]) + (p[10] + p[11])) + ((p[12] + p[13]) + (p[14] + p[15]));
      l[pp] += redsum32(ps);

      // PV B-frags: direct packs (V is perm16-interleaved in memory)
      union { unsigned int u[4]; short8 s8; } f0, f1;
#pragma unroll
      for (int i = 0; i < 4; ++i) {
        f0.u[i] = pkbf(p[2 * i], p[2 * i + 1]);
        f1.u[i] = pkbf(p[8 + 2 * i], p[9 + 2 * i]);
      }
      o[pp][0] = __builtin_amdgcn_mfma_f32_32x32x16_bf16(vf[0], f0.s8, o[pp][0], 0, 0, 0);
      o[pp][0] = __builtin_amdgcn_mfma_f32_32x32x16_bf16(vf[1], f1.s8, o[pp][0], 0, 0, 0);
      o[pp][1] = __builtin_amdgcn_mfma_f32_32x32x16_bf16(vf[2], f0.s8, o[pp][1], 0, 0, 0);
      o[pp][1] = __builtin_amdgcn_mfma_f32_32x32x16_bf16(vf[3], f1.s8, o[pp][1], 0, 0, 0);
    }

#pragma unroll
    for (int s = 0; s < 4; ++s) kf[s] = kn[s];
  }

  // epilogue: lane-local 1/l, store both parts
  const int b = bh >> 4, head = bh & 15;
#pragma unroll
  for (int pp = 0; pp < 2; ++pp) {
    const float inv = 1.0f / l[pp];
    unsigned short* Orow = O + ((size_t)(b * 2048 + q0[pp] + ql)) * 1024 + head * 64;
#pragma unroll
    for (int g = 0; g < 4; ++g) {
      {
        const unsigned int lo = pkbf(o[pp][0][g * 4 + 0] * inv, o[pp][0][g * 4 + 1] * inv);
        const unsigned int hi = pkbf(o[pp][0][g * 4 + 2] * inv, o[pp][0][g * 4 + 3] * inv);
        uint2 val; val.x = lo; val.y = hi;
        *(uint2*)(Orow + 8 * g + 4 * h) = val;
      }
      {
        const unsigned int lo = pkbf(o[pp][1][g * 4 + 0] * inv, o[pp][1][g * 4 + 1] * inv);
        const unsigned int hi = pkbf(o[pp][1][g * 4 + 2] * inv, o[pp][1][g * 4 + 3] * inv);
        uint2 val; val.x = lo; val.y = hi;
        *(uint2*)(Orow + 32 + 8 * g + 4 * h) = val;
      }
    }
  }
}

extern "C" void kernel_launch(void* const* d_in, const int* in_sizes, int n_in,
                              void* d_out, int out_size, void* d_ws, size_t ws_size,
                              hipStream_t stream) {
  (void)in_sizes; (void)n_in; (void)out_size; (void)ws_size;
  const float* x      = (const float*)d_in[0];
  const float* w_qkv  = (const float*)d_in[1];
  const float* w_proj = (const float*)d_in[2];
  float* out = (float*)d_out;
  char* ws = (char*)d_ws;

  unsigned short* x_bf   = (unsigned short*)(ws);              // 16 MB (reused as attn_out)
  unsigned short* wqT    = (unsigned short*)(ws + 16777216);   // 6 MB
  unsigned short* wpT    = (unsigned short*)(ws + 23068672);   // 2 MB
  unsigned short* Qd     = (unsigned short*)(ws + 25165824);   // 16 MB
  unsigned short* Kd     = (unsigned short*)(ws + 41943040);   // 16 MB
  unsigned short* Vd     = (unsigned short*)(ws + 58720256);   // 16 MB
  unsigned short* Vt     = (unsigned short*)(ws + 75497472);   // 16 MB
  unsigned short* attn_o = x_bf;

  cvt_bf16_kernel<<<4096, 256, 0, stream>>>(x, x_bf, 8388608);
  transpose_w_kernel<<<dim3(96, 32), 256, 0, stream>>>(w_qkv, wqT, 1024, 3072);
  transpose_w_kernel<<<dim3(32, 32), 256, 0, stream>>>(w_proj, wpT, 1024, 1024);
  gemm_bt_kernel<8192, 3072, 1024, 0><<<dim3(24, 64), 256, 0, stream>>>(
      x_bf, wqT, Qd, Kd, Vd, nullptr);
  transpose_v_kernel<<<dim3(32, 64), 256, 0, stream>>>(Vd, Vt);
  attn_kernel<<<512, 256, 0, stream>>>(Qd, Kd, Vt, attn_o);
  gemm_bt_kernel<8192, 1024, 1024, 1><<<dim3(8, 64), 256, 0, stream>>>(
      attn_o, wpT, nullptr, nullptr, nullptr, out);
}

// Round 6
// 221.082 us; speedup vs baseline: 2.5458x; 1.0197x over previous
//
#include <hip/hip_runtime.h>
#include <stdint.h>
#include <math.h>

typedef __attribute__((ext_vector_type(8))) short short8;
typedef __attribute__((ext_vector_type(4))) float f32x4;
typedef __attribute__((ext_vector_type(16))) float f32x16;

#define DEV __device__ __forceinline__

DEV unsigned short f2bf(float f) {
  union { float f; unsigned int u; } v; v.f = f;
  return (unsigned short)((v.u + 0x7FFFu + ((v.u >> 16) & 1u)) >> 16);
}

DEV unsigned int pkbf(float a, float b) {  // low16 = bf16(a), high16 = bf16(b)
  unsigned int r;
  asm("v_cvt_pk_bf16_f32 %0, %1, %2" : "=v"(r) : "v"(a), "v"(b));
  return r;
}

#if __has_builtin(__builtin_amdgcn_permlane32_swap)
DEV float redmax32(float v) {
  typedef __attribute__((ext_vector_type(2))) unsigned int uint2v;
  union { float f; unsigned int u; } c; c.f = v;
  uint2v r = __builtin_amdgcn_permlane32_swap(c.u, c.u, false, false);
  union { unsigned int u; float f; } a, b; a.u = r[0]; b.u = r[1];
  return fmaxf(a.f, b.f);
}
DEV float redsum32(float v) {
  typedef __attribute__((ext_vector_type(2))) unsigned int uint2v;
  union { float f; unsigned int u; } c; c.f = v;
  uint2v r = __builtin_amdgcn_permlane32_swap(c.u, c.u, false, false);
  union { unsigned int u; float f; } a, b; a.u = r[0]; b.u = r[1];
  return a.f + b.f;
}
#else
DEV float redmax32(float v) { return fmaxf(v, __shfl_xor(v, 32, 64)); }
DEV float redsum32(float v) { return v + __shfl_xor(v, 32, 64); }
#endif

DEV void gld16(const void* g, void* lds) {
  __builtin_amdgcn_global_load_lds(
      (const __attribute__((address_space(1))) unsigned int*)g,
      (__attribute__((address_space(3))) unsigned int*)lds, 16, 0, 0);
}

// ---------------- fp32 -> bf16 convert (8 elems/thread) ----------------
__global__ __launch_bounds__(256) void cvt_bf16_kernel(
    const float* __restrict__ in, unsigned short* __restrict__ out, int n) {
  int i = (blockIdx.x * 256 + threadIdx.x) * 8;
  if (i >= n) return;
  const float4 a = *(const float4*)(in + i);
  const float4 b = *(const float4*)(in + i + 4);
  short8 o;
  o[0] = (short)f2bf(a.x); o[1] = (short)f2bf(a.y);
  o[2] = (short)f2bf(a.z); o[3] = (short)f2bf(a.w);
  o[4] = (short)f2bf(b.x); o[5] = (short)f2bf(b.y);
  o[6] = (short)f2bf(b.z); o[7] = (short)f2bf(b.w);
  *(short8*)(out + i) = o;
}

// ------------- transpose fp32 (K x N) -> bf16 (N x K) ------------------
__global__ __launch_bounds__(256) void transpose_w_kernel(
    const float* __restrict__ in, unsigned short* __restrict__ out,
    int Kdim, int Ndim) {
  __shared__ float t[32][33];
  const int nb = blockIdx.x * 32, kb = blockIdx.y * 32;
  const int tx = threadIdx.x & 31, ty = threadIdx.x >> 5;  // ty 0..7
#pragma unroll
  for (int i = 0; i < 32; i += 8)
    t[ty + i][tx] = in[(size_t)(kb + ty + i) * Ndim + nb + tx];
  __syncthreads();
#pragma unroll
  for (int i = 0; i < 32; i += 8)
    out[(size_t)(nb + ty + i) * Kdim + kb + tx] = f2bf(t[tx][ty + i]);
}

// --------- transpose V (bh, s, 64) bf16 -> Vts (bh, 64, s') bf16 -------
// s' applies perm16 = swap bits 2,3 of (s mod 16) so that PV B-fragments
// are direct packs of the S^T D-fragment (no cross-lane exchange needed).
__global__ __launch_bounds__(256) void transpose_v_kernel(
    const unsigned short* __restrict__ V, unsigned short* __restrict__ Vt) {
  __shared__ __align__(16) unsigned short t[64][72];
  const int bh = blockIdx.y, s0 = blockIdx.x * 64;
  const int tid = threadIdx.x;
  const unsigned short* src = V + ((size_t)bh * 2048 + s0) * 64;
#pragma unroll
  for (int pass = 0; pass < 2; ++pass) {
    int r = (tid >> 3) + pass * 32;
    short8 v = *(const short8*)(src + r * 64 + (tid & 7) * 8);
    *(short8*)(&t[r][(tid & 7) * 8]) = v;
  }
  __syncthreads();
  unsigned short* dst = Vt + (size_t)bh * 64 * 2048 + s0;
#pragma unroll
  for (int pass = 0; pass < 2; ++pass) {
    int d = (tid >> 3) + pass * 32;
    int ss = (tid & 7) * 8;
    short8 v;
#pragma unroll
    for (int j = 0; j < 8; ++j) {
      const int u = ss + j;
      const int g = (u & ~12) | ((u & 4) << 1) | ((u & 8) >> 1);  // swap bits 2,3
      v[j] = (short)t[g][d];
    }
    *(short8*)(dst + (size_t)d * 2048 + ss) = v;
  }
}

// ---------------- GEMM: C(MxN) = A(MxK,bf16) * Bt(NxK,bf16)^T ----------
template<int M, int N, int K, int MODE>
__global__ __launch_bounds__(256)
void gemm_bt_kernel(const unsigned short* __restrict__ A,
                    const unsigned short* __restrict__ Bt,
                    unsigned short* __restrict__ Qd,
                    unsigned short* __restrict__ Kd,
                    unsigned short* __restrict__ Vd,
                    float* __restrict__ outC) {
  __shared__ __align__(16) unsigned short lsA[128 * 32];
  __shared__ __align__(16) unsigned short lsB[128 * 32];
  const int tid = threadIdx.x, wid = tid >> 6, lane = tid & 63;
  const int wr = wid >> 1, wc = wid & 1;
  const int m0 = blockIdx.y * 128, n0 = blockIdx.x * 128;

  f32x4 acc[4][4] = {};

  const int rA = lane >> 2, kA = (lane & 3) * 8;
  for (int kt = 0; kt < K / 32; ++kt) {
    __syncthreads();
#pragma unroll
    for (int c = 0; c < 2; ++c) {
      const int q = c * 4 + wid;
      gld16(A  + (size_t)(m0 + q * 16 + rA) * K + kt * 32 + kA, lsA + q * 512);
      gld16(Bt + (size_t)(n0 + q * 16 + rA) * K + kt * 32 + kA, lsB + q * 512);
    }
    __syncthreads();
    short8 af[4], bfr[4];
#pragma unroll
    for (int i = 0; i < 4; ++i) {
      af[i]  = *(const short8*)(lsA + (wr * 64 + i * 16 + (lane & 15)) * 32 + (lane >> 4) * 8);
      bfr[i] = *(const short8*)(lsB + (wc * 64 + i * 16 + (lane & 15)) * 32 + (lane >> 4) * 8);
    }
#pragma unroll
    for (int i = 0; i < 4; ++i)
#pragma unroll
      for (int j = 0; j < 4; ++j)
        acc[i][j] = __builtin_amdgcn_mfma_f32_16x16x32_bf16(af[i], bfr[j], acc[i][j], 0, 0, 0);
  }

#pragma unroll
  for (int i = 0; i < 4; ++i) {
#pragma unroll
    for (int j = 0; j < 4; ++j) {
      const int rbase = m0 + wr * 64 + i * 16 + (lane >> 4) * 4;
      const int col = n0 + wc * 64 + j * 16 + (lane & 15);
      if constexpr (MODE == 0) {
        const int which = col >> 10, h = (col >> 6) & 15, d = col & 63;
        unsigned short* dst = which == 0 ? Qd : (which == 1 ? Kd : Vd);
        // Q pre-scaled by rsqrt(hd)*log2(e) so attention uses exp2 directly
        const float scale = which == 0 ? 0.18033688f : 1.0f;
#pragma unroll
        for (int ii = 0; ii < 4; ++ii) {
          const int r = rbase + ii, b = r >> 11, s = r & 2047;
          dst[((size_t)(b * 16 + h) * 2048 + s) * 64 + d] = f2bf(acc[i][j][ii] * scale);
        }
      } else {
#pragma unroll
        for (int ii = 0; ii < 4; ++ii)
          outC[(size_t)(rbase + ii) * N + col] = acc[i][j][ii];
      }
    }
  }
}

// ---------------- causal flash attention helpers ----------------
DEV void loadK4(const unsigned short* Kb, int krow0, int ql, int h, short8 kf[4]) {
#pragma unroll
  for (int s = 0; s < 4; ++s)
    kf[s] = *(const short8*)(Kb + (size_t)(krow0 + ql) * 64 + s * 16 + h * 8);
}
DEV void loadV4(const unsigned short* Vb, int kv0, int ql, int h, short8 vf[4]) {
#pragma unroll
  for (int t2 = 0; t2 < 2; ++t2)
#pragma unroll
    for (int sl = 0; sl < 2; ++sl)
      vf[t2 * 2 + sl] = *(const short8*)(Vb + (size_t)(t2 * 32 + ql) * 2048 + kv0 + sl * 16 + h * 8);
}

// One KV-tile step for NP parts (NP=2: dual independent chains in one BB for
// ILP; NP=1: tail where only part B remains). MASK applies causal mask to
// part index 0 at this kv0 (used only for the peeled diagonal segments).
template<int NP, bool MASK>
DEV void attn_step(int kv0, const short8 kf[4], const short8 qf[][4],
                   const int q0[], const short8 vf[4],
                   float m[], float l[], f32x16 o[][2], int ql, int h) {
  // stage 1: S^T for all parts (independent MFMA chains)
  f32x16 st[NP];
#pragma unroll
  for (int pp = 0; pp < NP; ++pp) {
    f32x16 s = {};
#pragma unroll
    for (int ss = 0; ss < 4; ++ss)
      s = __builtin_amdgcn_mfma_f32_32x32x16_bf16(kf[ss], qf[pp][ss], s, 0, 0, 0);
    st[pp] = s;
  }
  if constexpr (MASK) {
#pragma unroll
    for (int r = 0; r < 16; ++r) {
      const int krow = (r & 3) + 8 * (r >> 2) + 4 * h;
      if (kv0 + krow > q0[0] + ql) st[0][r] = -INFINITY;
    }
  }
  // stage 2: tile maxes (independent trees)
  float pm[NP];
#pragma unroll
  for (int pp = 0; pp < NP; ++pp) {
    float a = fmaxf(fmaxf(fmaxf(st[pp][0], st[pp][1]), fmaxf(st[pp][2], st[pp][3])),
                    fmaxf(fmaxf(st[pp][4], st[pp][5]), fmaxf(st[pp][6], st[pp][7])));
    a = fmaxf(a, fmaxf(fmaxf(fmaxf(st[pp][8], st[pp][9]), fmaxf(st[pp][10], st[pp][11])),
                       fmaxf(fmaxf(st[pp][12], st[pp][13]), fmaxf(st[pp][14], st[pp][15]))));
    pm[pp] = redmax32(a);
  }
  // stage 3: combined defer-max rescale (one branch for all parts;
  // false-positive rescale is exact: exp2f(0) == 1)
  bool need = false;
#pragma unroll
  for (int pp = 0; pp < NP; ++pp) need = need || (pm[pp] > m[pp] + 11.5f);
  if (__any(need)) {
#pragma unroll
    for (int pp = 0; pp < NP; ++pp) {
      const float mn = fmaxf(m[pp], pm[pp]);
      const float al = exp2f(m[pp] - mn);
      m[pp] = mn;
      l[pp] *= al;
#pragma unroll
      for (int r = 0; r < 16; ++r) { o[pp][0][r] *= al; o[pp][1][r] *= al; }
    }
  }
  // stage 4: exp2 + sum + pack per part (p lifetime local to pp)
  union pk_t { unsigned int u[4]; short8 s8; };
  pk_t f0[NP], f1[NP];
#pragma unroll
  for (int pp = 0; pp < NP; ++pp) {
    float p[16];
#pragma unroll
    for (int r = 0; r < 16; ++r) p[r] = exp2f(st[pp][r] - m[pp]);
    float ps = ((p[0] + p[1]) + (p[2] + p[3])) + ((p[4] + p[5]) + (p[6] + p[7]));
    ps += ((p[8] + p[9]) + (p[10] + p[11])) + ((p[12] + p[13]) + (p[14] + p[15]));
    l[pp] += redsum32(ps);
#pragma unroll
    for (int i = 0; i < 4; ++i) {
      f0[pp].u[i] = pkbf(p[2 * i], p[2 * i + 1]);
      f1[pp].u[i] = pkbf(p[8 + 2 * i], p[9 + 2 * i]);
    }
  }
  // stage 5: PV (2*NP independent MFMA chains of depth 2)
#pragma unroll
  for (int pp = 0; pp < NP; ++pp) {
    o[pp][0] = __builtin_amdgcn_mfma_f32_32x32x16_bf16(vf[0], f0[pp].s8, o[pp][0], 0, 0, 0);
    o[pp][0] = __builtin_amdgcn_mfma_f32_32x32x16_bf16(vf[1], f1[pp].s8, o[pp][0], 0, 0, 0);
    o[pp][1] = __builtin_amdgcn_mfma_f32_32x32x16_bf16(vf[2], f0[pp].s8, o[pp][1], 0, 0, 0);
    o[pp][1] = __builtin_amdgcn_mfma_f32_32x32x16_bf16(vf[3], f1[pp].s8, o[pp][1], 0, 0, 0);
  }
}

// ---------------- causal flash attention, paired q-tiles ----------------
// grid 512 1-D, XCD-swizzled decode (bh = id&63 -> all 8 walkers of a bh on
// one XCD; K/V L2-resident). Wave owns q-tiles qtA = w*4+wid (0..31) and
// qtB = 63-qtA: 65 tile-parts, uniform. NO barrier (no shared state), no
// dummy iterations. Four branch-free segments: [0,qtA) dual-part,
// {qtA} dual-part+maskA, (qtA,qtB) B-only, {qtB} B+maskB. Dual-part
// segments expose two independent softmax/PV chains to the scheduler.
__global__ __launch_bounds__(256, 2)
void attn_kernel(const unsigned short* __restrict__ Q,
                 const unsigned short* __restrict__ Kc,
                 const unsigned short* __restrict__ Vts,
                 unsigned short* __restrict__ O) {
  const int bh = blockIdx.x & 63;
  const int w  = blockIdx.x >> 6;            // 0..7, walker 0 = heaviest
  const int wid = threadIdx.x >> 6, lane = threadIdx.x & 63;
  const int ql = lane & 31, h = lane >> 5;
  const int qtA = w * 4 + wid;               // 0..31
  const int qtB = 63 - qtA;                  // 32..63
  const int q0[2] = {qtA * 32, qtB * 32};

  const unsigned short* Qb = Q   + (size_t)bh * 2048 * 64;
  const unsigned short* Kb = Kc  + (size_t)bh * 2048 * 64;
  const unsigned short* Vb = Vts + (size_t)bh * 64 * 2048;

  short8 qf[2][4];
#pragma unroll
  for (int pp = 0; pp < 2; ++pp)
#pragma unroll
    for (int s = 0; s < 4; ++s)
      qf[pp][s] = *(const short8*)(Qb + (size_t)(q0[pp] + ql) * 64 + s * 16 + h * 8);

  f32x16 o[2][2] = {};               // [part][d-half], O^T: col q, rows d
  float m[2] = {-INFINITY, -INFINITY};
  float l[2] = {0.f, 0.f};

  short8 kf[4], kn[4], vf[4];
  loadK4(Kb, 0, ql, h, kf);

  // segment 1: t in [0, qtA) -- both parts, no mask
  for (int t = 0; t < qtA; ++t) {
    const int kv0 = t * 32;
    loadV4(Vb, kv0, ql, h, vf);
    loadK4(Kb, kv0 + 32, ql, h, kn);           // <= 992: in-bounds
    attn_step<2, false>(kv0, kf, qf, q0, vf, m, l, o, ql, h);
#pragma unroll
    for (int s = 0; s < 4; ++s) kf[s] = kn[s];
  }
  // segment 2: t = qtA -- both parts, mask part A (B unmasked: qtA < qtB)
  {
    const int kv0 = qtA * 32;
    loadV4(Vb, kv0, ql, h, vf);
    loadK4(Kb, kv0 + 32, ql, h, kn);           // <= 1024: in-bounds
    attn_step<2, true>(kv0, kf, qf, q0, vf, m, l, o, ql, h);
#pragma unroll
    for (int s = 0; s < 4; ++s) kf[s] = kn[s];
  }
  // segment 3: t in (qtA, qtB) -- part B only
  for (int t = qtA + 1; t < qtB; ++t) {
    const int kv0 = t * 32;
    loadV4(Vb, kv0, ql, h, vf);
    loadK4(Kb, kv0 + 32, ql, h, kn);           // t < qtB <= 63 -> <= 2016: in-bounds
    attn_step<1, false>(kv0, kf, &qf[1], &q0[1], vf, &m[1], &l[1], &o[1], ql, h);
#pragma unroll
    for (int s = 0; s < 4; ++s) kf[s] = kn[s];
  }
  // segment 4: t = qtB -- part B, masked, no prefetch
  {
    const int kv0 = qtB * 32;
    loadV4(Vb, kv0, ql, h, vf);
    attn_step<1, true>(kv0, kf, &qf[1], &q0[1], vf, &m[1], &l[1], &o[1], ql, h);
  }

  // epilogue: lane-local 1/l, store both parts
  const int b = bh >> 4, head = bh & 15;
#pragma unroll
  for (int pp = 0; pp < 2; ++pp) {
    const float inv = 1.0f / l[pp];
    unsigned short* Orow = O + ((size_t)(b * 2048 + q0[pp] + ql)) * 1024 + head * 64;
#pragma unroll
    for (int g = 0; g < 4; ++g) {
      {
        const unsigned int lo = pkbf(o[pp][0][g * 4 + 0] * inv, o[pp][0][g * 4 + 1] * inv);
        const unsigned int hi = pkbf(o[pp][0][g * 4 + 2] * inv, o[pp][0][g * 4 + 3] * inv);
        uint2 val; val.x = lo; val.y = hi;
        *(uint2*)(Orow + 8 * g + 4 * h) = val;
      }
      {
        const unsigned int lo = pkbf(o[pp][1][g * 4 + 0] * inv, o[pp][1][g * 4 + 1] * inv);
        const unsigned int hi = pkbf(o[pp][1][g * 4 + 2] * inv, o[pp][1][g * 4 + 3] * inv);
        uint2 val; val.x = lo; val.y = hi;
        *(uint2*)(Orow + 32 + 8 * g + 4 * h) = val;
      }
    }
  }
}

extern "C" void kernel_launch(void* const* d_in, const int* in_sizes, int n_in,
                              void* d_out, int out_size, void* d_ws, size_t ws_size,
                              hipStream_t stream) {
  (void)in_sizes; (void)n_in; (void)out_size; (void)ws_size;
  const float* x      = (const float*)d_in[0];
  const float* w_qkv  = (const float*)d_in[1];
  const float* w_proj = (const float*)d_in[2];
  float* out = (float*)d_out;
  char* ws = (char*)d_ws;

  unsigned short* x_bf   = (unsigned short*)(ws);              // 16 MB (reused as attn_out)
  unsigned short* wqT    = (unsigned short*)(ws + 16777216);   // 6 MB
  unsigned short* wpT    = (unsigned short*)(ws + 23068672);   // 2 MB
  unsigned short* Qd     = (unsigned short*)(ws + 25165824);   // 16 MB
  unsigned short* Kd     = (unsigned short*)(ws + 41943040);   // 16 MB
  unsigned short* Vd     = (unsigned short*)(ws + 58720256);   // 16 MB
  unsigned short* Vt     = (unsigned short*)(ws + 75497472);   // 16 MB
  unsigned short* attn_o = x_bf;

  cvt_bf16_kernel<<<4096, 256, 0, stream>>>(x, x_bf, 8388608);
  transpose_w_kernel<<<dim3(96, 32), 256, 0, stream>>>(w_qkv, wqT, 1024, 3072);
  transpose_w_kernel<<<dim3(32, 32), 256, 0, stream>>>(w_proj, wpT, 1024, 1024);
  gemm_bt_kernel<8192, 3072, 1024, 0><<<dim3(24, 64), 256, 0, stream>>>(
      x_bf, wqT, Qd, Kd, Vd, nullptr);
  transpose_v_kernel<<<dim3(32, 64), 256, 0, stream>>>(Vd, Vt);
  attn_kernel<<<512, 256, 0, stream>>>(Qd, Kd, Vt, attn_o);
  gemm_bt_kernel<8192, 1024, 1024, 1><<<dim3(8, 64), 256, 0, stream>>>(
      attn_o, wpT, nullptr, nullptr, nullptr, out);
}